// Round 13
// baseline (4048.986 us; speedup 1.0000x reference)
//
#include <hip/hip_runtime.h>

// Problem constants
#define Bsz 131072
#define Dd  256
#define Ll  4
#define Kk  1024
#define RW  16                 // rows per wave (one MFMA A-tile)
#define NWG 2048               // blocks of 4 waves x 16 rows = 64 rows
#define NT  256
#define CAPW 160               // candidate capacity per wave per level
#define MARGIN 0.05f           // >> 2x worst-case bf16 screening error

// Output layout (element offsets into float32 d_out, concat in return order)
#define O_IDX   0ULL                                   // indices      [B][L]
#define O_QSTK  524288ULL                              // quant_stack  [B][L][D]
#define O_QSUM  (O_QSTK + (size_t)Bsz * Ll * Dd)       // quant_sum    [B][D]
#define O_QSQ   (O_QSUM + (size_t)Bsz * Dd)            // quant_sum_qs [B][D]
#define O_RES   (O_QSQ  + (size_t)Bsz * Dd)            // res_states   [L+1][B][D]
#define O_LOSS  (O_RES  + (size_t)(Ll + 1) * Bsz * Dd) // 3 scalars

// ws layout (floats): [0,32768) per-wave/level ssq; [32768,36864) c2;
// [40960, +1M shorts) bf16 codebook
#define WS_C2_OFF  32768
#define WS_CBH_OFF 40960

typedef short v8s __attribute__((ext_vector_type(8)));
typedef float v4f __attribute__((ext_vector_type(4)));

__device__ __forceinline__ unsigned short f2bf(float f) {   // RNE f32->bf16
    unsigned u = __float_as_uint(f);
    return (unsigned short)((u + 0x7fffu + ((u >> 16) & 1u)) >> 16);
}

// ---------------------------------------------------------------------------
// numpy-mirror row sum-of-squares, serial form (used by prep kernel)
// ---------------------------------------------------------------------------
__device__ __forceinline__ float np_rowsum_sq(const float* a) {
    float blk[2];
    #pragma unroll
    for (int hb = 0; hb < 2; ++hb) {
        const float* p = a + hb * 128;
        float r8[8][4];
        #pragma unroll
        for (int j = 0; j < 8; ++j) {
            float4 x = *(const float4*)(p + 4 * j);
            r8[j][0] = __fmul_rn(x.x, x.x);
            r8[j][1] = __fmul_rn(x.y, x.y);
            r8[j][2] = __fmul_rn(x.z, x.z);
            r8[j][3] = __fmul_rn(x.w, x.w);
        }
        #pragma unroll
        for (int i = 32; i < 128; i += 32) {
            #pragma unroll
            for (int j = 0; j < 8; ++j) {
                float4 x = *(const float4*)(p + i + 4 * j);
                r8[j][0] = __fadd_rn(r8[j][0], __fmul_rn(x.x, x.x));
                r8[j][1] = __fadd_rn(r8[j][1], __fmul_rn(x.y, x.y));
                r8[j][2] = __fadd_rn(r8[j][2], __fmul_rn(x.z, x.z));
                r8[j][3] = __fadd_rn(r8[j][3], __fmul_rn(x.w, x.w));
            }
        }
        float wv[4];
        #pragma unroll
        for (int L = 0; L < 4; ++L) {
            wv[L] = __fadd_rn(
                __fadd_rn(__fadd_rn(r8[0][L], r8[1][L]), __fadd_rn(r8[2][L], r8[3][L])),
                __fadd_rn(__fadd_rn(r8[4][L], r8[5][L]), __fadd_rn(r8[6][L], r8[7][L])));
        }
        blk[hb] = __fadd_rn(__fadd_rn(wv[0], wv[1]), __fadd_rn(wv[2], wv[3]));
    }
    return __fadd_rn(blk[0], blk[1]);
}

__global__ void prep_kernel(const float* __restrict__ cbks, float* __restrict__ ws) {
    int t = blockIdx.x * 256 + threadIdx.x;
    if (t < Ll * Kk) ws[WS_C2_OFF + t] = np_rowsum_sq(cbks + (size_t)t * Dd);
}

// bf16 copy of codebook, same [l][k][d] layout
__global__ void cvt_kernel(const float* __restrict__ cbks, float* __restrict__ ws) {
    unsigned short* cbh = (unsigned short*)(ws + WS_CBH_OFF);
    int i = (blockIdx.x * 256 + threadIdx.x) * 4;
    float4 x = *(const float4*)(cbks + i);
    ushort4 y;
    y.x = f2bf(x.x); y.y = f2bf(x.y); y.z = f2bf(x.z); y.w = f2bf(x.w);
    *(ushort4*)(cbh + i) = y;
}

// ---------------------------------------------------------------------------
// main kernel: each WAVE autonomously owns 16 rows, residual in REGISTERS.
// Layout: lane (r = lane&15, hi = lane>>4) holds res[ks][j] =
//         residual[row r][d = ks*32 + hi*8 + j]  == MFMA A-fragment layout.
// No __syncthreads anywhere; waves share nothing.
// ---------------------------------------------------------------------------
__global__ __launch_bounds__(NT, 3) void rvq_kernel(
    const float* __restrict__ ze, const float* __restrict__ cbks,
    float* __restrict__ out, float* __restrict__ ws)
{
    __shared__ unsigned long long best64[4 * RW];
    __shared__ int clist[4 * CAPW];
    __shared__ int cc[4];

    const int tid  = threadIdx.x;
    const int w    = tid >> 6;
    const int lane = tid & 63;
    const int r    = lane & 15;
    const int hi   = lane >> 4;
    const int rows0 = blockIdx.x * 64 + w * RW;
    const size_t grow = (size_t)(rows0 + r);

    const float* c2 = ws + WS_C2_OFF;
    const unsigned short* cbh = (const unsigned short*)(ws + WS_CBH_OFF);

    float res[8][8];   // [ks][j], static-indexed everywhere

    // ---- init: load ze into regs, write residual_states[0] ----
    #pragma unroll
    for (int ks = 0; ks < 8; ++ks) {
        const int d0 = ks * 32 + hi * 8;
        float4 z0 = *(const float4*)(ze + grow * Dd + d0);
        float4 z1 = *(const float4*)(ze + grow * Dd + d0 + 4);
        res[ks][0] = z0.x; res[ks][1] = z0.y; res[ks][2] = z0.z; res[ks][3] = z0.w;
        res[ks][4] = z1.x; res[ks][5] = z1.y; res[ks][6] = z1.z; res[ks][7] = z1.w;
        *(float4*)(out + O_RES + grow * Dd + d0)     = z0;
        *(float4*)(out + O_RES + grow * Dd + d0 + 4) = z1;
    }

    for (int l = 0; l < Ll; ++l) {
        // ---- np-exact r2 from registers (commutativity-based tree) ----
        float blk[2];
        #pragma unroll
        for (int hb = 0; hb < 2; ++hb) {
            float wv[4];
            #pragma unroll
            for (int L = 0; L < 4; ++L) {
                float a0 = __fmul_rn(res[4*hb][L],     res[4*hb][L]);
                float a1 = __fmul_rn(res[4*hb][4 + L], res[4*hb][4 + L]);
                #pragma unroll
                for (int m = 1; m < 4; ++m) {
                    a0 = __fadd_rn(a0, __fmul_rn(res[4*hb+m][L],     res[4*hb+m][L]));
                    a1 = __fadd_rn(a1, __fmul_rn(res[4*hb+m][4 + L], res[4*hb+m][4 + L]));
                }
                float p = __fadd_rn(a0, a1);                 // r8[2hi]+r8[2hi+1]
                float q = __fadd_rn(p, __shfl_xor(p, 16));   // pair hi groups
                wv[L]   = __fadd_rn(q, __shfl_xor(q, 32));   // all 8 accs
            }
            blk[hb] = __fadd_rn(__fadd_rn(wv[0], wv[1]), __fadd_rn(wv[2], wv[3]));
        }
        const float r2v = __fadd_rn(blk[0], blk[1]);   // every lane: r2 of row r

        if (lane < RW) best64[w * RW + lane] = ~0ull;
        if (lane == 0) cc[w] = 0;

        // ---- bf16 A fragments (in-register) ----
        v8s abf[8];
        #pragma unroll
        for (int ks = 0; ks < 8; ++ks) {
            v8s t;
            #pragma unroll
            for (int j = 0; j < 8; ++j) t[j] = (short)f2bf(res[ks][j]);
            abf[ks] = t;
        }

        const unsigned short* cbh_l = cbh + (size_t)l * Kk * Dd;
        const float* c2l = c2 + l * Kk;
        const float* cb  = cbks + (size_t)l * Kk * Dd;

        // ---- screen: 16 chunks x 64 codes, running row-min, collect ----
        float mr[4] = {1e30f, 1e30f, 1e30f, 1e30f};
        for (int ch = 0; ch < 16; ++ch) {
            const int cbase = ch * 64;
            v4f acc[4];
            #pragma unroll
            for (int ct = 0; ct < 4; ++ct) acc[ct] = (v4f)(0.f);
            #pragma unroll
            for (int ks = 0; ks < 8; ++ks) {
                #pragma unroll
                for (int ct = 0; ct < 4; ++ct) {
                    v8s b = *(const v8s*)(cbh_l + (size_t)(cbase + ct*16 + r) * Dd
                                          + ks * 32 + hi * 8);
                    acc[ct] = __builtin_amdgcn_mfma_f32_16x16x32_bf16(abf[ks], b, acc[ct], 0, 0, 0);
                }
            }
            float c2v[4];
            #pragma unroll
            for (int ct = 0; ct < 4; ++ct) c2v[ct] = c2l[cbase + ct*16 + r];
            #pragma unroll
            for (int reg = 0; reg < 4; ++reg) {
                const int lrow = hi * 4 + reg;     // C-layout residual row
                float t0 = c2v[0] - 2.f * acc[0][reg];
                float t1 = c2v[1] - 2.f * acc[1][reg];
                float t2 = c2v[2] - 2.f * acc[2][reg];
                float t3 = c2v[3] - 2.f * acc[3][reg];
                float pm = fminf(fminf(t0, t1), fminf(t2, t3));
                pm = fminf(pm, __shfl_xor(pm, 1));
                pm = fminf(pm, __shfl_xor(pm, 2));
                pm = fminf(pm, __shfl_xor(pm, 4));
                pm = fminf(pm, __shfl_xor(pm, 8));
                float nm = fminf(mr[reg], pm);
                mr[reg] = nm;
                float th = nm + MARGIN;
                if (t0 < th) { int p = atomicAdd(&cc[w], 1); if (p < CAPW) clist[w*CAPW+p] = (lrow << 10) | (cbase + r); }
                if (t1 < th) { int p = atomicAdd(&cc[w], 1); if (p < CAPW) clist[w*CAPW+p] = (lrow << 10) | (cbase + 16 + r); }
                if (t2 < th) { int p = atomicAdd(&cc[w], 1); if (p < CAPW) clist[w*CAPW+p] = (lrow << 10) | (cbase + 32 + r); }
                if (t3 < th) { int p = atomicAdd(&cc[w], 1); if (p < CAPW) clist[w*CAPW+p] = (lrow << 10) | (cbase + 48 + r); }
            }
        }

        // ---- exact np-order rescore; residual via uniform-exec shfl ----
        {
            int cnt = cc[w];
            const bool ok = (cnt <= CAPW);
            const int total = ok ? cnt : (RW * Kk);
            for (int base = 0; base < total; base += 64) {
                const int ci = base + lane;
                int rr, code;
                if (ok) {
                    int rc = clist[w * CAPW + (ci < cnt ? ci : 0)];
                    rr = rc >> 10; code = rc & 1023;
                } else {
                    rr = ci >> 10; code = ci & 1023;
                }
                const float* cp = cb + (size_t)code * Dd;
                const float r2row = __shfl(r2v, rr);
                float a = 0.f;
                #pragma unroll
                for (int ks = 0; ks < 8; ++ks) {
                    #pragma unroll
                    for (int hh = 0; hh < 4; ++hh) {
                        const int src = rr + (hh << 4);
                        float4 c0 = *(const float4*)(cp + ks * 32 + hh * 8);
                        float4 c1 = *(const float4*)(cp + ks * 32 + hh * 8 + 4);
                        a = __fmaf_rn(__shfl(res[ks][0], src), c0.x, a);
                        a = __fmaf_rn(__shfl(res[ks][1], src), c0.y, a);
                        a = __fmaf_rn(__shfl(res[ks][2], src), c0.z, a);
                        a = __fmaf_rn(__shfl(res[ks][3], src), c0.w, a);
                        a = __fmaf_rn(__shfl(res[ks][4], src), c1.x, a);
                        a = __fmaf_rn(__shfl(res[ks][5], src), c1.y, a);
                        a = __fmaf_rn(__shfl(res[ks][6], src), c1.z, a);
                        a = __fmaf_rn(__shfl(res[ks][7], src), c1.w, a);
                    }
                }
                float s = __fsub_rn(__fadd_rn(r2row, c2l[code]), 2.0f * a);
                if (!ok || ci < cnt) {
                    unsigned long long pk =
                        (((unsigned long long)__float_as_uint(s)) << 32) | (unsigned)code;
                    atomicMin(&best64[w * RW + rr], pk);
                }
            }
        }

        // ---- gather chosen code, update regs, emit outputs (exact) ----
        unsigned long long bb = best64[w * RW + r];
        const int idx = (int)(bb & 0xffffffffu);
        if (lane < RW)
            out[O_IDX + (size_t)(rows0 + lane) * Ll + l] =
                (float)(int)(best64[w * RW + lane] & 0xffffffffu);

        const float* qp = cb + (size_t)idx * Dd;
        float ssq = 0.f;
        #pragma unroll
        for (int ks = 0; ks < 8; ++ks) {
            const int d0 = ks * 32 + hi * 8;
            float4 q0 = *(const float4*)(qp + d0);
            float4 q1 = *(const float4*)(qp + d0 + 4);
            res[ks][0] = __fsub_rn(res[ks][0], q0.x);
            res[ks][1] = __fsub_rn(res[ks][1], q0.y);
            res[ks][2] = __fsub_rn(res[ks][2], q0.z);
            res[ks][3] = __fsub_rn(res[ks][3], q0.w);
            res[ks][4] = __fsub_rn(res[ks][4], q1.x);
            res[ks][5] = __fsub_rn(res[ks][5], q1.y);
            res[ks][6] = __fsub_rn(res[ks][6], q1.z);
            res[ks][7] = __fsub_rn(res[ks][7], q1.w);
            *(float4*)(out + O_QSTK + ((grow * Ll) + l) * Dd + d0)     = q0;
            *(float4*)(out + O_QSTK + ((grow * Ll) + l) * Dd + d0 + 4) = q1;
            float4 n0 = make_float4(res[ks][0], res[ks][1], res[ks][2], res[ks][3]);
            float4 n1 = make_float4(res[ks][4], res[ks][5], res[ks][6], res[ks][7]);
            *(float4*)(out + O_RES + ((size_t)(l + 1) * Bsz + grow) * Dd + d0)     = n0;
            *(float4*)(out + O_RES + ((size_t)(l + 1) * Bsz + grow) * Dd + d0 + 4) = n1;
            ssq += n0.x*n0.x + n0.y*n0.y + n0.z*n0.z + n0.w*n0.w
                 + n1.x*n1.x + n1.y*n1.y + n1.z*n1.z + n1.w*n1.w;
        }
        #pragma unroll
        for (int m = 32; m; m >>= 1) ssq += __shfl_xor(ssq, m);
        if (lane == 0)
            ws[((size_t)blockIdx.x * 4 + w) * 4 + l] = ssq;
    }

    // ---- epilogue: quantized_sum / qspace from register residual ----
    #pragma unroll
    for (int ks = 0; ks < 8; ++ks) {
        const int d0 = ks * 32 + hi * 8;
        float4 z0 = *(const float4*)(ze + grow * Dd + d0);
        float4 z1 = *(const float4*)(ze + grow * Dd + d0 + 4);
        float4 qs0 = make_float4(z0.x - res[ks][0], z0.y - res[ks][1],
                                 z0.z - res[ks][2], z0.w - res[ks][3]);
        float4 qs1 = make_float4(z1.x - res[ks][4], z1.y - res[ks][5],
                                 z1.z - res[ks][6], z1.w - res[ks][7]);
        *(float4*)(out + O_QSUM + grow * Dd + d0)     = qs0;
        *(float4*)(out + O_QSUM + grow * Dd + d0 + 4) = qs1;
        float4 qq0 = make_float4(z0.x + (qs0.x - z0.x), z0.y + (qs0.y - z0.y),
                                 z0.z + (qs0.z - z0.z), z0.w + (qs0.w - z0.w));
        float4 qq1 = make_float4(z1.x + (qs1.x - z1.x), z1.y + (qs1.y - z1.y),
                                 z1.z + (qs1.z - z1.z), z1.w + (qs1.w - z1.w));
        *(float4*)(out + O_QSQ + grow * Dd + d0)     = qq0;
        *(float4*)(out + O_QSQ + grow * Dd + d0 + 4) = qq1;
    }
}

// ---------------------------------------------------------------------------
// loss: deterministic reduction of per-wave partials -> 3 scalars
// ---------------------------------------------------------------------------
__global__ void loss_kernel(const float* __restrict__ ws, float* __restrict__ out) {
    __shared__ float red[Ll * 4];
    int tid = threadIdx.x;
    int lane = tid & 63, w = tid >> 6;
    for (int l = 0; l < Ll; ++l) {
        float s = 0.f;
        for (int i = tid; i < NWG * 4; i += 256) s += ws[i * 4 + l];
        #pragma unroll
        for (int m = 32; m; m >>= 1) s += __shfl_xor(s, m);
        if (lane == 0) red[l * 4 + w] = s;
    }
    __syncthreads();
    if (tid == 0) {
        float tot = 0.f;
        for (int l = 0; l < Ll; ++l)
            tot += red[l * 4 + 0] + red[l * 4 + 1] + red[l * 4 + 2] + red[l * 4 + 3];
        float cm = tot / (float)((size_t)Ll * Bsz * Dd);
        out[O_LOSS + 0] = cm;                    // commitment_loss
        out[O_LOSS + 1] = cm;                    // codebook_loss
        out[O_LOSS + 2] = 0.25f * cm + cm;       // quantization_loss
    }
}

extern "C" void kernel_launch(void* const* d_in, const int* in_sizes, int n_in,
                              void* d_out, int out_size, void* d_ws, size_t ws_size,
                              hipStream_t stream) {
    (void)in_sizes; (void)n_in; (void)out_size; (void)ws_size;
    const float* ze   = (const float*)d_in[0];
    const float* cbks = (const float*)d_in[1];
    float* out = (float*)d_out;
    float* ws  = (float*)d_ws;

    hipLaunchKernelGGL(prep_kernel, dim3(16), dim3(256), 0, stream, cbks, ws);
    hipLaunchKernelGGL(cvt_kernel, dim3(Ll * Kk * Dd / 1024), dim3(256), 0, stream, cbks, ws);
    hipLaunchKernelGGL(rvq_kernel, dim3(NWG), dim3(NT), 0, stream, ze, cbks, out, ws);
    hipLaunchKernelGGL(loss_kernel, dim3(1), dim3(256), 0, stream, ws, out);
}

// Round 14
// 3729.763 us; speedup vs baseline: 1.0856x; 1.0856x over previous
//
#include <hip/hip_runtime.h>

// Problem constants
#define Bsz 131072
#define Dd  256
#define Ll  4
#define Kk  1024
#define RW  16                 // rows per wave (one MFMA A-tile)
#define NWG 2048               // blocks of 4 waves x 16 rows = 64 rows
#define NT  256
#define CAPW 160               // candidate capacity per wave per level
#define MARGIN 0.05f           // >> 2x worst-case bf16 screening error

// Output layout (element offsets into float32 d_out, concat in return order)
#define O_IDX   0ULL                                   // indices      [B][L]
#define O_QSTK  524288ULL                              // quant_stack  [B][L][D]
#define O_QSUM  (O_QSTK + (size_t)Bsz * Ll * Dd)       // quant_sum    [B][D]
#define O_QSQ   (O_QSUM + (size_t)Bsz * Dd)            // quant_sum_qs [B][D]
#define O_RES   (O_QSQ  + (size_t)Bsz * Dd)            // res_states   [L+1][B][D]
#define O_LOSS  (O_RES  + (size_t)(Ll + 1) * Bsz * Dd) // 3 scalars

// ws layout (floats): [0,32768) per-wave/level ssq (8192x4); [32768,36864) c2;
// [40960, +1M shorts) bf16 codebook
#define WS_C2_OFF  32768
#define WS_CBH_OFF 40960

typedef short v8s __attribute__((ext_vector_type(8)));
typedef float v4f __attribute__((ext_vector_type(4)));

__device__ __forceinline__ unsigned short f2bf(float f) {   // RNE f32->bf16
    unsigned u = __float_as_uint(f);
    return (unsigned short)((u + 0x7fffu + ((u >> 16) & 1u)) >> 16);
}

// ---------------------------------------------------------------------------
// numpy-mirror row sum-of-squares, serial form (used by prep kernel)
// ---------------------------------------------------------------------------
__device__ __forceinline__ float np_rowsum_sq(const float* a) {
    float blk[2];
    #pragma unroll
    for (int hb = 0; hb < 2; ++hb) {
        const float* p = a + hb * 128;
        float r8[8][4];
        #pragma unroll
        for (int j = 0; j < 8; ++j) {
            float4 x = *(const float4*)(p + 4 * j);
            r8[j][0] = __fmul_rn(x.x, x.x);
            r8[j][1] = __fmul_rn(x.y, x.y);
            r8[j][2] = __fmul_rn(x.z, x.z);
            r8[j][3] = __fmul_rn(x.w, x.w);
        }
        #pragma unroll
        for (int i = 32; i < 128; i += 32) {
            #pragma unroll
            for (int j = 0; j < 8; ++j) {
                float4 x = *(const float4*)(p + i + 4 * j);
                r8[j][0] = __fadd_rn(r8[j][0], __fmul_rn(x.x, x.x));
                r8[j][1] = __fadd_rn(r8[j][1], __fmul_rn(x.y, x.y));
                r8[j][2] = __fadd_rn(r8[j][2], __fmul_rn(x.z, x.z));
                r8[j][3] = __fadd_rn(r8[j][3], __fmul_rn(x.w, x.w));
            }
        }
        float wv[4];
        #pragma unroll
        for (int L = 0; L < 4; ++L) {
            wv[L] = __fadd_rn(
                __fadd_rn(__fadd_rn(r8[0][L], r8[1][L]), __fadd_rn(r8[2][L], r8[3][L])),
                __fadd_rn(__fadd_rn(r8[4][L], r8[5][L]), __fadd_rn(r8[6][L], r8[7][L])));
        }
        blk[hb] = __fadd_rn(__fadd_rn(wv[0], wv[1]), __fadd_rn(wv[2], wv[3]));
    }
    return __fadd_rn(blk[0], blk[1]);
}

__global__ void prep_kernel(const float* __restrict__ cbks, float* __restrict__ ws) {
    int t = blockIdx.x * 256 + threadIdx.x;
    if (t < Ll * Kk) ws[WS_C2_OFF + t] = np_rowsum_sq(cbks + (size_t)t * Dd);
}

// bf16 copy of codebook, same [l][k][d] layout
__global__ void cvt_kernel(const float* __restrict__ cbks, float* __restrict__ ws) {
    unsigned short* cbh = (unsigned short*)(ws + WS_CBH_OFF);
    int i = (blockIdx.x * 256 + threadIdx.x) * 4;
    float4 x = *(const float4*)(cbks + i);
    ushort4 y;
    y.x = f2bf(x.x); y.y = f2bf(x.y); y.z = f2bf(x.z); y.w = f2bf(x.w);
    *(ushort4*)(cbh + i) = y;
}

// ---------------------------------------------------------------------------
// Kernel A (select): each WAVE autonomously owns 16 rows in registers.
// Writes ONLY the chosen indices. No __syncthreads, ~3 KB LDS.
// ---------------------------------------------------------------------------
__global__ __launch_bounds__(NT, 4) void sel_kernel(
    const float* __restrict__ ze, const float* __restrict__ cbks,
    float* __restrict__ out, float* __restrict__ ws)
{
    __shared__ unsigned long long best64[4 * RW];
    __shared__ int clist[4 * CAPW];
    __shared__ int cc[4];

    const int tid  = threadIdx.x;
    const int w    = tid >> 6;
    const int lane = tid & 63;
    const int r    = lane & 15;
    const int hi   = lane >> 4;
    const int rows0 = blockIdx.x * 64 + w * RW;
    const size_t grow = (size_t)(rows0 + r);

    const float* c2 = ws + WS_C2_OFF;
    const unsigned short* cbh = (const unsigned short*)(ws + WS_CBH_OFF);

    float res[8][8];   // [ks][j]: residual[row r][d = ks*32 + hi*8 + j]

    #pragma unroll
    for (int ks = 0; ks < 8; ++ks) {
        const int d0 = ks * 32 + hi * 8;
        float4 z0 = *(const float4*)(ze + grow * Dd + d0);
        float4 z1 = *(const float4*)(ze + grow * Dd + d0 + 4);
        res[ks][0] = z0.x; res[ks][1] = z0.y; res[ks][2] = z0.z; res[ks][3] = z0.w;
        res[ks][4] = z1.x; res[ks][5] = z1.y; res[ks][6] = z1.z; res[ks][7] = z1.w;
    }

    for (int l = 0; l < Ll; ++l) {
        // ---- np-exact r2 from registers (commutativity-based tree) ----
        float blk[2];
        #pragma unroll
        for (int hb = 0; hb < 2; ++hb) {
            float wv[4];
            #pragma unroll
            for (int L = 0; L < 4; ++L) {
                float a0 = __fmul_rn(res[4*hb][L],     res[4*hb][L]);
                float a1 = __fmul_rn(res[4*hb][4 + L], res[4*hb][4 + L]);
                #pragma unroll
                for (int m = 1; m < 4; ++m) {
                    a0 = __fadd_rn(a0, __fmul_rn(res[4*hb+m][L],     res[4*hb+m][L]));
                    a1 = __fadd_rn(a1, __fmul_rn(res[4*hb+m][4 + L], res[4*hb+m][4 + L]));
                }
                float p = __fadd_rn(a0, a1);
                float q = __fadd_rn(p, __shfl_xor(p, 16));
                wv[L]   = __fadd_rn(q, __shfl_xor(q, 32));
            }
            blk[hb] = __fadd_rn(__fadd_rn(wv[0], wv[1]), __fadd_rn(wv[2], wv[3]));
        }
        const float r2v = __fadd_rn(blk[0], blk[1]);

        if (lane < RW) best64[w * RW + lane] = ~0ull;
        if (lane == 0) cc[w] = 0;

        // ---- bf16 A fragments (in-register) ----
        v8s abf[8];
        #pragma unroll
        for (int ks = 0; ks < 8; ++ks) {
            v8s t;
            #pragma unroll
            for (int j = 0; j < 8; ++j) t[j] = (short)f2bf(res[ks][j]);
            abf[ks] = t;
        }

        const unsigned short* cbh_l = cbh + (size_t)l * Kk * Dd;
        const float* c2l = c2 + l * Kk;
        const float* cb  = cbks + (size_t)l * Kk * Dd;

        // ---- screen: 16 chunks x 64 codes ----
        float mr[4] = {1e30f, 1e30f, 1e30f, 1e30f};
        for (int ch = 0; ch < 16; ++ch) {
            const int cbase = ch * 64;
            v4f acc[4];
            #pragma unroll
            for (int ct = 0; ct < 4; ++ct) acc[ct] = (v4f)(0.f);
            #pragma unroll
            for (int ks = 0; ks < 8; ++ks) {
                #pragma unroll
                for (int ct = 0; ct < 4; ++ct) {
                    v8s b = *(const v8s*)(cbh_l + (size_t)(cbase + ct*16 + r) * Dd
                                          + ks * 32 + hi * 8);
                    acc[ct] = __builtin_amdgcn_mfma_f32_16x16x32_bf16(abf[ks], b, acc[ct], 0, 0, 0);
                }
            }
            float c2v[4];
            #pragma unroll
            for (int ct = 0; ct < 4; ++ct) c2v[ct] = c2l[cbase + ct*16 + r];
            #pragma unroll
            for (int reg = 0; reg < 4; ++reg) {
                const int lrow = hi * 4 + reg;
                float t0 = c2v[0] - 2.f * acc[0][reg];
                float t1 = c2v[1] - 2.f * acc[1][reg];
                float t2 = c2v[2] - 2.f * acc[2][reg];
                float t3 = c2v[3] - 2.f * acc[3][reg];
                float pm = fminf(fminf(t0, t1), fminf(t2, t3));
                pm = fminf(pm, __shfl_xor(pm, 1));
                pm = fminf(pm, __shfl_xor(pm, 2));
                pm = fminf(pm, __shfl_xor(pm, 4));
                pm = fminf(pm, __shfl_xor(pm, 8));
                float nm = fminf(mr[reg], pm);
                mr[reg] = nm;
                float th = nm + MARGIN;
                if (t0 < th) { int p = atomicAdd(&cc[w], 1); if (p < CAPW) clist[w*CAPW+p] = (lrow << 10) | (cbase + r); }
                if (t1 < th) { int p = atomicAdd(&cc[w], 1); if (p < CAPW) clist[w*CAPW+p] = (lrow << 10) | (cbase + 16 + r); }
                if (t2 < th) { int p = atomicAdd(&cc[w], 1); if (p < CAPW) clist[w*CAPW+p] = (lrow << 10) | (cbase + 32 + r); }
                if (t3 < th) { int p = atomicAdd(&cc[w], 1); if (p < CAPW) clist[w*CAPW+p] = (lrow << 10) | (cbase + 48 + r); }
            }
        }

        // ---- exact np-order rescore; residual via uniform-exec shfl ----
        {
            int cnt = cc[w];
            const bool ok = (cnt <= CAPW);
            const int total = ok ? cnt : (RW * Kk);
            for (int base = 0; base < total; base += 64) {
                const int ci = base + lane;
                int rr, code;
                if (ok) {
                    int rc = clist[w * CAPW + (ci < cnt ? ci : 0)];
                    rr = rc >> 10; code = rc & 1023;
                } else {
                    rr = ci >> 10; code = ci & 1023;
                }
                const float* cp = cb + (size_t)code * Dd;
                const float r2row = __shfl(r2v, rr);
                float a = 0.f;
                #pragma unroll
                for (int ks = 0; ks < 8; ++ks) {
                    #pragma unroll
                    for (int hh = 0; hh < 4; ++hh) {
                        const int src = rr + (hh << 4);
                        float4 c0 = *(const float4*)(cp + ks * 32 + hh * 8);
                        float4 c1 = *(const float4*)(cp + ks * 32 + hh * 8 + 4);
                        a = __fmaf_rn(__shfl(res[ks][0], src), c0.x, a);
                        a = __fmaf_rn(__shfl(res[ks][1], src), c0.y, a);
                        a = __fmaf_rn(__shfl(res[ks][2], src), c0.z, a);
                        a = __fmaf_rn(__shfl(res[ks][3], src), c0.w, a);
                        a = __fmaf_rn(__shfl(res[ks][4], src), c1.x, a);
                        a = __fmaf_rn(__shfl(res[ks][5], src), c1.y, a);
                        a = __fmaf_rn(__shfl(res[ks][6], src), c1.z, a);
                        a = __fmaf_rn(__shfl(res[ks][7], src), c1.w, a);
                    }
                }
                float s = __fsub_rn(__fadd_rn(r2row, c2l[code]), 2.0f * a);
                if (!ok || ci < cnt) {
                    unsigned long long pk =
                        (((unsigned long long)__float_as_uint(s)) << 32) | (unsigned)code;
                    atomicMin(&best64[w * RW + rr], pk);
                }
            }
        }

        // ---- pick index, update register residual (exact), store idx ----
        const int idx = (int)(best64[w * RW + r] & 0xffffffffu);
        if (lane < RW)
            out[O_IDX + (size_t)(rows0 + lane) * Ll + l] =
                (float)(int)(best64[w * RW + lane] & 0xffffffffu);

        if (l < Ll - 1) {
            const float* qp = cb + (size_t)idx * Dd;
            #pragma unroll
            for (int ks = 0; ks < 8; ++ks) {
                const int d0 = ks * 32 + hi * 8;
                float4 q0 = *(const float4*)(qp + d0);
                float4 q1 = *(const float4*)(qp + d0 + 4);
                res[ks][0] = __fsub_rn(res[ks][0], q0.x);
                res[ks][1] = __fsub_rn(res[ks][1], q0.y);
                res[ks][2] = __fsub_rn(res[ks][2], q0.z);
                res[ks][3] = __fsub_rn(res[ks][3], q0.w);
                res[ks][4] = __fsub_rn(res[ks][4], q1.x);
                res[ks][5] = __fsub_rn(res[ks][5], q1.y);
                res[ks][6] = __fsub_rn(res[ks][6], q1.z);
                res[ks][7] = __fsub_rn(res[ks][7], q1.w);
            }
        }
    }
}

// ---------------------------------------------------------------------------
// Kernel B (materialize): streaming reconstruction from indices.
// One wave per row-pass; lane i covers floats [4i, 4i+4) -> 1 KB per
// instruction across the wave, fully coalesced. Computes ssq partials.
// ---------------------------------------------------------------------------
__global__ __launch_bounds__(NT, 8) void mat_kernel(
    const float* __restrict__ ze, const float* __restrict__ cbks,
    float* __restrict__ out, float* __restrict__ ws)
{
    const int tid  = threadIdx.x;
    const int w    = tid >> 6;
    const int lane = tid & 63;
    const int wgid = blockIdx.x * 4 + w;      // 0..8191
    const int d0   = lane * 4;

    float ssql[4] = {0.f, 0.f, 0.f, 0.f};

    #pragma unroll 1
    for (int rr = 0; rr < 16; ++rr) {
        const size_t row = (size_t)wgid + (size_t)rr * 8192;

        int idx[4];
        #pragma unroll
        for (int l = 0; l < Ll; ++l)
            idx[l] = (int)out[O_IDX + row * Ll + l];

        float4 q[4];
        #pragma unroll
        for (int l = 0; l < Ll; ++l)
            q[l] = *(const float4*)(cbks + ((size_t)l * Kk + idx[l]) * Dd + d0);

        float4 z = *(const float4*)(ze + row * Dd + d0);
        *(float4*)(out + O_RES + row * Dd + d0) = z;         // res_states[0]

        float4 r = z;
        #pragma unroll
        for (int l = 0; l < Ll; ++l) {
            *(float4*)(out + O_QSTK + (row * Ll + l) * Dd + d0) = q[l];
            r.x = __fsub_rn(r.x, q[l].x);
            r.y = __fsub_rn(r.y, q[l].y);
            r.z = __fsub_rn(r.z, q[l].z);
            r.w = __fsub_rn(r.w, q[l].w);
            *(float4*)(out + O_RES + ((size_t)(l + 1) * Bsz + row) * Dd + d0) = r;
            ssql[l] += r.x * r.x + r.y * r.y + r.z * r.z + r.w * r.w;
        }

        float4 qs = make_float4(z.x - r.x, z.y - r.y, z.z - r.z, z.w - r.w);
        *(float4*)(out + O_QSUM + row * Dd + d0) = qs;
        float4 qq = make_float4(z.x + (qs.x - z.x), z.y + (qs.y - z.y),
                                z.z + (qs.z - z.z), z.w + (qs.w - z.w));
        *(float4*)(out + O_QSQ + row * Dd + d0) = qq;
    }

    #pragma unroll
    for (int l = 0; l < Ll; ++l) {
        float s = ssql[l];
        #pragma unroll
        for (int m = 32; m; m >>= 1) s += __shfl_xor(s, m);
        if (lane == 0) ws[(size_t)wgid * 4 + l] = s;
    }
}

// ---------------------------------------------------------------------------
// loss: deterministic reduction of per-wave partials -> 3 scalars
// ---------------------------------------------------------------------------
__global__ void loss_kernel(const float* __restrict__ ws, float* __restrict__ out) {
    __shared__ float red[Ll * 4];
    int tid = threadIdx.x;
    int lane = tid & 63, w = tid >> 6;
    for (int l = 0; l < Ll; ++l) {
        float s = 0.f;
        for (int i = tid; i < NWG * 4; i += 256) s += ws[i * 4 + l];
        #pragma unroll
        for (int m = 32; m; m >>= 1) s += __shfl_xor(s, m);
        if (lane == 0) red[l * 4 + w] = s;
    }
    __syncthreads();
    if (tid == 0) {
        float tot = 0.f;
        for (int l = 0; l < Ll; ++l)
            tot += red[l * 4 + 0] + red[l * 4 + 1] + red[l * 4 + 2] + red[l * 4 + 3];
        float cm = tot / (float)((size_t)Ll * Bsz * Dd);
        out[O_LOSS + 0] = cm;                    // commitment_loss
        out[O_LOSS + 1] = cm;                    // codebook_loss
        out[O_LOSS + 2] = 0.25f * cm + cm;       // quantization_loss
    }
}

extern "C" void kernel_launch(void* const* d_in, const int* in_sizes, int n_in,
                              void* d_out, int out_size, void* d_ws, size_t ws_size,
                              hipStream_t stream) {
    (void)in_sizes; (void)n_in; (void)out_size; (void)ws_size;
    const float* ze   = (const float*)d_in[0];
    const float* cbks = (const float*)d_in[1];
    float* out = (float*)d_out;
    float* ws  = (float*)d_ws;

    hipLaunchKernelGGL(prep_kernel, dim3(16), dim3(256), 0, stream, cbks, ws);
    hipLaunchKernelGGL(cvt_kernel, dim3(Ll * Kk * Dd / 1024), dim3(256), 0, stream, cbks, ws);
    hipLaunchKernelGGL(sel_kernel, dim3(NWG), dim3(NT), 0, stream, ze, cbks, out, ws);
    hipLaunchKernelGGL(mat_kernel, dim3(NWG), dim3(NT), 0, stream, ze, cbks, out, ws);
    hipLaunchKernelGGL(loss_kernel, dim3(1), dim3(256), 0, stream, ws, out);
}

// Round 15
// 3239.290 us; speedup vs baseline: 1.2500x; 1.1514x over previous
//
#include <hip/hip_runtime.h>

// Problem constants
#define Bsz 131072
#define Dd  256
#define Ll  4
#define Kk  1024
#define RW  16                 // rows per wave (one MFMA A-tile)
#define NWG 2048               // blocks of 4 waves x 16 rows = 64 rows
#define NT  256
#define CAPW 160               // candidate capacity per wave per level
#define MARGIN 0.05f           // >> 2x worst-case bf16 screening error

// Output layout (element offsets into float32 d_out, concat in return order)
#define O_IDX   0ULL                                   // indices      [B][L]
#define O_QSTK  524288ULL                              // quant_stack  [B][L][D]
#define O_QSUM  (O_QSTK + (size_t)Bsz * Ll * Dd)       // quant_sum    [B][D]
#define O_QSQ   (O_QSUM + (size_t)Bsz * Dd)            // quant_sum_qs [B][D]
#define O_RES   (O_QSQ  + (size_t)Bsz * Dd)            // res_states   [L+1][B][D]
#define O_LOSS  (O_RES  + (size_t)(Ll + 1) * Bsz * Dd) // 3 scalars

// ws layout (floats): [0,32768) per-wave/level ssq (8192x4); [32768,36864) c2;
// [40960, +1M shorts) bf16 codebook
#define WS_C2_OFF  32768
#define WS_CBH_OFF 40960

typedef short v8s __attribute__((ext_vector_type(8)));
typedef float v4f __attribute__((ext_vector_type(4)));

__device__ __forceinline__ unsigned short f2bf(float f) {   // RNE f32->bf16
    unsigned u = __float_as_uint(f);
    return (unsigned short)((u + 0x7fffu + ((u >> 16) & 1u)) >> 16);
}

// ---------------------------------------------------------------------------
// numpy-mirror row sum-of-squares, serial form (used by prep kernel)
// ---------------------------------------------------------------------------
__device__ __forceinline__ float np_rowsum_sq(const float* a) {
    float blk[2];
    #pragma unroll
    for (int hb = 0; hb < 2; ++hb) {
        const float* p = a + hb * 128;
        float r8[8][4];
        #pragma unroll
        for (int j = 0; j < 8; ++j) {
            float4 x = *(const float4*)(p + 4 * j);
            r8[j][0] = __fmul_rn(x.x, x.x);
            r8[j][1] = __fmul_rn(x.y, x.y);
            r8[j][2] = __fmul_rn(x.z, x.z);
            r8[j][3] = __fmul_rn(x.w, x.w);
        }
        #pragma unroll
        for (int i = 32; i < 128; i += 32) {
            #pragma unroll
            for (int j = 0; j < 8; ++j) {
                float4 x = *(const float4*)(p + i + 4 * j);
                r8[j][0] = __fadd_rn(r8[j][0], __fmul_rn(x.x, x.x));
                r8[j][1] = __fadd_rn(r8[j][1], __fmul_rn(x.y, x.y));
                r8[j][2] = __fadd_rn(r8[j][2], __fmul_rn(x.z, x.z));
                r8[j][3] = __fadd_rn(r8[j][3], __fmul_rn(x.w, x.w));
            }
        }
        float wv[4];
        #pragma unroll
        for (int L = 0; L < 4; ++L) {
            wv[L] = __fadd_rn(
                __fadd_rn(__fadd_rn(r8[0][L], r8[1][L]), __fadd_rn(r8[2][L], r8[3][L])),
                __fadd_rn(__fadd_rn(r8[4][L], r8[5][L]), __fadd_rn(r8[6][L], r8[7][L])));
        }
        blk[hb] = __fadd_rn(__fadd_rn(wv[0], wv[1]), __fadd_rn(wv[2], wv[3]));
    }
    return __fadd_rn(blk[0], blk[1]);
}

__global__ void prep_kernel(const float* __restrict__ cbks, float* __restrict__ ws) {
    int t = blockIdx.x * 256 + threadIdx.x;
    if (t < Ll * Kk) ws[WS_C2_OFF + t] = np_rowsum_sq(cbks + (size_t)t * Dd);
}

// bf16 copy of codebook, same [l][k][d] layout
__global__ void cvt_kernel(const float* __restrict__ cbks, float* __restrict__ ws) {
    unsigned short* cbh = (unsigned short*)(ws + WS_CBH_OFF);
    int i = (blockIdx.x * 256 + threadIdx.x) * 4;
    float4 x = *(const float4*)(cbks + i);
    ushort4 y;
    y.x = f2bf(x.x); y.y = f2bf(x.y); y.z = f2bf(x.z); y.w = f2bf(x.w);
    *(ushort4*)(cbh + i) = y;
}

// ---------------------------------------------------------------------------
// Kernel A (select): each WAVE autonomously owns 16 rows in registers.
// Writes ONLY the chosen indices. No __syncthreads, ~3 KB LDS.
// __launch_bounds__(NT, 1): do NOT cap VGPRs — res[8][8] must stay in regs
// (R14's (NT,4) clamped to 64 VGPR and spilled 5 GB of scratch traffic).
// ---------------------------------------------------------------------------
__global__ __launch_bounds__(NT, 1) void sel_kernel(
    const float* __restrict__ ze, const float* __restrict__ cbks,
    float* __restrict__ out, float* __restrict__ ws)
{
    __shared__ unsigned long long best64[4 * RW];
    __shared__ int clist[4 * CAPW];
    __shared__ int cc[4];

    const int tid  = threadIdx.x;
    const int w    = tid >> 6;
    const int lane = tid & 63;
    const int r    = lane & 15;
    const int hi   = lane >> 4;
    const int rows0 = blockIdx.x * 64 + w * RW;
    const size_t grow = (size_t)(rows0 + r);

    const float* c2 = ws + WS_C2_OFF;
    const unsigned short* cbh = (const unsigned short*)(ws + WS_CBH_OFF);

    float res[8][8];   // [ks][j]: residual[row r][d = ks*32 + hi*8 + j]

    #pragma unroll
    for (int ks = 0; ks < 8; ++ks) {
        const int d0 = ks * 32 + hi * 8;
        float4 z0 = *(const float4*)(ze + grow * Dd + d0);
        float4 z1 = *(const float4*)(ze + grow * Dd + d0 + 4);
        res[ks][0] = z0.x; res[ks][1] = z0.y; res[ks][2] = z0.z; res[ks][3] = z0.w;
        res[ks][4] = z1.x; res[ks][5] = z1.y; res[ks][6] = z1.z; res[ks][7] = z1.w;
    }

    for (int l = 0; l < Ll; ++l) {
        // ---- np-exact r2 from registers (commutativity-based tree) ----
        float blk[2];
        #pragma unroll
        for (int hb = 0; hb < 2; ++hb) {
            float wv[4];
            #pragma unroll
            for (int L = 0; L < 4; ++L) {
                float a0 = __fmul_rn(res[4*hb][L],     res[4*hb][L]);
                float a1 = __fmul_rn(res[4*hb][4 + L], res[4*hb][4 + L]);
                #pragma unroll
                for (int m = 1; m < 4; ++m) {
                    a0 = __fadd_rn(a0, __fmul_rn(res[4*hb+m][L],     res[4*hb+m][L]));
                    a1 = __fadd_rn(a1, __fmul_rn(res[4*hb+m][4 + L], res[4*hb+m][4 + L]));
                }
                float p = __fadd_rn(a0, a1);
                float q = __fadd_rn(p, __shfl_xor(p, 16));
                wv[L]   = __fadd_rn(q, __shfl_xor(q, 32));
            }
            blk[hb] = __fadd_rn(__fadd_rn(wv[0], wv[1]), __fadd_rn(wv[2], wv[3]));
        }
        const float r2v = __fadd_rn(blk[0], blk[1]);

        if (lane < RW) best64[w * RW + lane] = ~0ull;
        if (lane == 0) cc[w] = 0;

        // ---- bf16 A fragments (in-register) ----
        v8s abf[8];
        #pragma unroll
        for (int ks = 0; ks < 8; ++ks) {
            v8s t;
            #pragma unroll
            for (int j = 0; j < 8; ++j) t[j] = (short)f2bf(res[ks][j]);
            abf[ks] = t;
        }

        const unsigned short* cbh_l = cbh + (size_t)l * Kk * Dd;
        const float* c2l = c2 + l * Kk;
        const float* cb  = cbks + (size_t)l * Kk * Dd;

        // ---- screen: 16 chunks x 64 codes ----
        float mr[4] = {1e30f, 1e30f, 1e30f, 1e30f};
        for (int ch = 0; ch < 16; ++ch) {
            const int cbase = ch * 64;
            v4f acc[4];
            #pragma unroll
            for (int ct = 0; ct < 4; ++ct) acc[ct] = (v4f)(0.f);
            #pragma unroll
            for (int ks = 0; ks < 8; ++ks) {
                #pragma unroll
                for (int ct = 0; ct < 4; ++ct) {
                    v8s b = *(const v8s*)(cbh_l + (size_t)(cbase + ct*16 + r) * Dd
                                          + ks * 32 + hi * 8);
                    acc[ct] = __builtin_amdgcn_mfma_f32_16x16x32_bf16(abf[ks], b, acc[ct], 0, 0, 0);
                }
            }
            float c2v[4];
            #pragma unroll
            for (int ct = 0; ct < 4; ++ct) c2v[ct] = c2l[cbase + ct*16 + r];
            #pragma unroll
            for (int reg = 0; reg < 4; ++reg) {
                const int lrow = hi * 4 + reg;
                float t0 = c2v[0] - 2.f * acc[0][reg];
                float t1 = c2v[1] - 2.f * acc[1][reg];
                float t2 = c2v[2] - 2.f * acc[2][reg];
                float t3 = c2v[3] - 2.f * acc[3][reg];
                float pm = fminf(fminf(t0, t1), fminf(t2, t3));
                pm = fminf(pm, __shfl_xor(pm, 1));
                pm = fminf(pm, __shfl_xor(pm, 2));
                pm = fminf(pm, __shfl_xor(pm, 4));
                pm = fminf(pm, __shfl_xor(pm, 8));
                float nm = fminf(mr[reg], pm);
                mr[reg] = nm;
                float th = nm + MARGIN;
                if (t0 < th) { int p = atomicAdd(&cc[w], 1); if (p < CAPW) clist[w*CAPW+p] = (lrow << 10) | (cbase + r); }
                if (t1 < th) { int p = atomicAdd(&cc[w], 1); if (p < CAPW) clist[w*CAPW+p] = (lrow << 10) | (cbase + 16 + r); }
                if (t2 < th) { int p = atomicAdd(&cc[w], 1); if (p < CAPW) clist[w*CAPW+p] = (lrow << 10) | (cbase + 32 + r); }
                if (t3 < th) { int p = atomicAdd(&cc[w], 1); if (p < CAPW) clist[w*CAPW+p] = (lrow << 10) | (cbase + 48 + r); }
            }
        }

        // ---- exact np-order rescore; residual via uniform-exec shfl ----
        {
            int cnt = cc[w];
            const bool ok = (cnt <= CAPW);
            const int total = ok ? cnt : (RW * Kk);
            for (int base = 0; base < total; base += 64) {
                const int ci = base + lane;
                int rr, code;
                if (ok) {
                    int rc = clist[w * CAPW + (ci < cnt ? ci : 0)];
                    rr = rc >> 10; code = rc & 1023;
                } else {
                    rr = ci >> 10; code = ci & 1023;
                }
                const float* cp = cb + (size_t)code * Dd;
                const float r2row = __shfl(r2v, rr);
                float a = 0.f;
                #pragma unroll
                for (int ks = 0; ks < 8; ++ks) {
                    #pragma unroll
                    for (int hh = 0; hh < 4; ++hh) {
                        const int src = rr + (hh << 4);
                        float4 c0 = *(const float4*)(cp + ks * 32 + hh * 8);
                        float4 c1 = *(const float4*)(cp + ks * 32 + hh * 8 + 4);
                        a = __fmaf_rn(__shfl(res[ks][0], src), c0.x, a);
                        a = __fmaf_rn(__shfl(res[ks][1], src), c0.y, a);
                        a = __fmaf_rn(__shfl(res[ks][2], src), c0.z, a);
                        a = __fmaf_rn(__shfl(res[ks][3], src), c0.w, a);
                        a = __fmaf_rn(__shfl(res[ks][4], src), c1.x, a);
                        a = __fmaf_rn(__shfl(res[ks][5], src), c1.y, a);
                        a = __fmaf_rn(__shfl(res[ks][6], src), c1.z, a);
                        a = __fmaf_rn(__shfl(res[ks][7], src), c1.w, a);
                    }
                }
                float s = __fsub_rn(__fadd_rn(r2row, c2l[code]), 2.0f * a);
                if (!ok || ci < cnt) {
                    unsigned long long pk =
                        (((unsigned long long)__float_as_uint(s)) << 32) | (unsigned)code;
                    atomicMin(&best64[w * RW + rr], pk);
                }
            }
        }

        // ---- pick index, update register residual (exact), store idx ----
        const int idx = (int)(best64[w * RW + r] & 0xffffffffu);
        if (lane < RW)
            out[O_IDX + (size_t)(rows0 + lane) * Ll + l] =
                (float)(int)(best64[w * RW + lane] & 0xffffffffu);

        if (l < Ll - 1) {
            const float* qp = cb + (size_t)idx * Dd;
            #pragma unroll
            for (int ks = 0; ks < 8; ++ks) {
                const int d0 = ks * 32 + hi * 8;
                float4 q0 = *(const float4*)(qp + d0);
                float4 q1 = *(const float4*)(qp + d0 + 4);
                res[ks][0] = __fsub_rn(res[ks][0], q0.x);
                res[ks][1] = __fsub_rn(res[ks][1], q0.y);
                res[ks][2] = __fsub_rn(res[ks][2], q0.z);
                res[ks][3] = __fsub_rn(res[ks][3], q0.w);
                res[ks][4] = __fsub_rn(res[ks][4], q1.x);
                res[ks][5] = __fsub_rn(res[ks][5], q1.y);
                res[ks][6] = __fsub_rn(res[ks][6], q1.z);
                res[ks][7] = __fsub_rn(res[ks][7], q1.w);
            }
        }
    }
}

// ---------------------------------------------------------------------------
// Kernel B (materialize): streaming reconstruction from indices.
// One wave per row-pass; lane i covers floats [4i, 4i+4) -> 1 KB per
// instruction across the wave, fully coalesced. Computes ssq partials.
// ---------------------------------------------------------------------------
__global__ __launch_bounds__(NT, 8) void mat_kernel(
    const float* __restrict__ ze, const float* __restrict__ cbks,
    float* __restrict__ out, float* __restrict__ ws)
{
    const int tid  = threadIdx.x;
    const int w    = tid >> 6;
    const int lane = tid & 63;
    const int wgid = blockIdx.x * 4 + w;      // 0..8191
    const int d0   = lane * 4;

    float ssql[4] = {0.f, 0.f, 0.f, 0.f};

    #pragma unroll 1
    for (int rr = 0; rr < 16; ++rr) {
        const size_t row = (size_t)wgid + (size_t)rr * 8192;

        int idx[4];
        #pragma unroll
        for (int l = 0; l < Ll; ++l)
            idx[l] = (int)out[O_IDX + row * Ll + l];

        float4 q[4];
        #pragma unroll
        for (int l = 0; l < Ll; ++l)
            q[l] = *(const float4*)(cbks + ((size_t)l * Kk + idx[l]) * Dd + d0);

        float4 z = *(const float4*)(ze + row * Dd + d0);
        *(float4*)(out + O_RES + row * Dd + d0) = z;         // res_states[0]

        float4 r = z;
        #pragma unroll
        for (int l = 0; l < Ll; ++l) {
            *(float4*)(out + O_QSTK + (row * Ll + l) * Dd + d0) = q[l];
            r.x = __fsub_rn(r.x, q[l].x);
            r.y = __fsub_rn(r.y, q[l].y);
            r.z = __fsub_rn(r.z, q[l].z);
            r.w = __fsub_rn(r.w, q[l].w);
            *(float4*)(out + O_RES + ((size_t)(l + 1) * Bsz + row) * Dd + d0) = r;
            ssql[l] += r.x * r.x + r.y * r.y + r.z * r.z + r.w * r.w;
        }

        float4 qs = make_float4(z.x - r.x, z.y - r.y, z.z - r.z, z.w - r.w);
        *(float4*)(out + O_QSUM + row * Dd + d0) = qs;
        float4 qq = make_float4(z.x + (qs.x - z.x), z.y + (qs.y - z.y),
                                z.z + (qs.z - z.z), z.w + (qs.w - z.w));
        *(float4*)(out + O_QSQ + row * Dd + d0) = qq;
    }

    #pragma unroll
    for (int l = 0; l < Ll; ++l) {
        float s = ssql[l];
        #pragma unroll
        for (int m = 32; m; m >>= 1) s += __shfl_xor(s, m);
        if (lane == 0) ws[(size_t)wgid * 4 + l] = s;
    }
}

// ---------------------------------------------------------------------------
// loss: deterministic reduction of per-wave partials -> 3 scalars
// ---------------------------------------------------------------------------
__global__ void loss_kernel(const float* __restrict__ ws, float* __restrict__ out) {
    __shared__ float red[Ll * 4];
    int tid = threadIdx.x;
    int lane = tid & 63, w = tid >> 6;
    for (int l = 0; l < Ll; ++l) {
        float s = 0.f;
        for (int i = tid; i < NWG * 4; i += 256) s += ws[i * 4 + l];
        #pragma unroll
        for (int m = 32; m; m >>= 1) s += __shfl_xor(s, m);
        if (lane == 0) red[l * 4 + w] = s;
    }
    __syncthreads();
    if (tid == 0) {
        float tot = 0.f;
        for (int l = 0; l < Ll; ++l)
            tot += red[l * 4 + 0] + red[l * 4 + 1] + red[l * 4 + 2] + red[l * 4 + 3];
        float cm = tot / (float)((size_t)Ll * Bsz * Dd);
        out[O_LOSS + 0] = cm;                    // commitment_loss
        out[O_LOSS + 1] = cm;                    // codebook_loss
        out[O_LOSS + 2] = 0.25f * cm + cm;       // quantization_loss
    }
}

extern "C" void kernel_launch(void* const* d_in, const int* in_sizes, int n_in,
                              void* d_out, int out_size, void* d_ws, size_t ws_size,
                              hipStream_t stream) {
    (void)in_sizes; (void)n_in; (void)out_size; (void)ws_size;
    const float* ze   = (const float*)d_in[0];
    const float* cbks = (const float*)d_in[1];
    float* out = (float*)d_out;
    float* ws  = (float*)d_ws;

    hipLaunchKernelGGL(prep_kernel, dim3(16), dim3(256), 0, stream, cbks, ws);
    hipLaunchKernelGGL(cvt_kernel, dim3(Ll * Kk * Dd / 1024), dim3(256), 0, stream, cbks, ws);
    hipLaunchKernelGGL(sel_kernel, dim3(NWG), dim3(NT), 0, stream, ze, cbks, out, ws);
    hipLaunchKernelGGL(mat_kernel, dim3(NWG), dim3(NT), 0, stream, ze, cbks, out, ws);
    hipLaunchKernelGGL(loss_kernel, dim3(1), dim3(256), 0, stream, ws, out);
}

// Round 16
// 2753.173 us; speedup vs baseline: 1.4707x; 1.1766x over previous
//
#include <hip/hip_runtime.h>

// Problem constants
#define Bsz 131072
#define Dd  256
#define Ll  4
#define Kk  1024
#define RW  16                 // rows per wave (one MFMA A-tile)
#define NWG 2048               // blocks of 4 waves x 16 rows = 64 rows
#define NT  256
#define CAPW 160               // candidate capacity per wave per level
#define MARGIN 0.05f           // >> 2x worst-case bf16 screening error

// Output layout (element offsets into float32 d_out, concat in return order)
#define O_IDX   0ULL                                   // indices      [B][L]
#define O_QSTK  524288ULL                              // quant_stack  [B][L][D]
#define O_QSUM  (O_QSTK + (size_t)Bsz * Ll * Dd)       // quant_sum    [B][D]
#define O_QSQ   (O_QSUM + (size_t)Bsz * Dd)            // quant_sum_qs [B][D]
#define O_RES   (O_QSQ  + (size_t)Bsz * Dd)            // res_states   [L+1][B][D]
#define O_LOSS  (O_RES  + (size_t)(Ll + 1) * Bsz * Dd) // 3 scalars

// ws layout (floats): [0,32768) per-wave/level ssq (8192x4); [32768,36864) c2;
// [40960, +1M shorts) bf16 codebook
#define WS_C2_OFF  32768
#define WS_CBH_OFF 40960

typedef short v8s __attribute__((ext_vector_type(8)));
typedef float v4f __attribute__((ext_vector_type(4)));

__device__ __forceinline__ unsigned short f2bf(float f) {   // RNE f32->bf16
    unsigned u = __float_as_uint(f);
    return (unsigned short)((u + 0x7fffu + ((u >> 16) & 1u)) >> 16);
}

// ---------------------------------------------------------------------------
// numpy-mirror row sum-of-squares, serial form (used by prep kernel)
// ---------------------------------------------------------------------------
__device__ __forceinline__ float np_rowsum_sq(const float* a) {
    float blk[2];
    #pragma unroll
    for (int hb = 0; hb < 2; ++hb) {
        const float* p = a + hb * 128;
        float r8[8][4];
        #pragma unroll
        for (int j = 0; j < 8; ++j) {
            float4 x = *(const float4*)(p + 4 * j);
            r8[j][0] = __fmul_rn(x.x, x.x);
            r8[j][1] = __fmul_rn(x.y, x.y);
            r8[j][2] = __fmul_rn(x.z, x.z);
            r8[j][3] = __fmul_rn(x.w, x.w);
        }
        #pragma unroll
        for (int i = 32; i < 128; i += 32) {
            #pragma unroll
            for (int j = 0; j < 8; ++j) {
                float4 x = *(const float4*)(p + i + 4 * j);
                r8[j][0] = __fadd_rn(r8[j][0], __fmul_rn(x.x, x.x));
                r8[j][1] = __fadd_rn(r8[j][1], __fmul_rn(x.y, x.y));
                r8[j][2] = __fadd_rn(r8[j][2], __fmul_rn(x.z, x.z));
                r8[j][3] = __fadd_rn(r8[j][3], __fmul_rn(x.w, x.w));
            }
        }
        float wv[4];
        #pragma unroll
        for (int L = 0; L < 4; ++L) {
            wv[L] = __fadd_rn(
                __fadd_rn(__fadd_rn(r8[0][L], r8[1][L]), __fadd_rn(r8[2][L], r8[3][L])),
                __fadd_rn(__fadd_rn(r8[4][L], r8[5][L]), __fadd_rn(r8[6][L], r8[7][L])));
        }
        blk[hb] = __fadd_rn(__fadd_rn(wv[0], wv[1]), __fadd_rn(wv[2], wv[3]));
    }
    return __fadd_rn(blk[0], blk[1]);
}

__global__ void prep_kernel(const float* __restrict__ cbks, float* __restrict__ ws) {
    int t = blockIdx.x * 256 + threadIdx.x;
    if (t < Ll * Kk) ws[WS_C2_OFF + t] = np_rowsum_sq(cbks + (size_t)t * Dd);
}

// bf16 copy of codebook, same [l][k][d] layout
__global__ void cvt_kernel(const float* __restrict__ cbks, float* __restrict__ ws) {
    unsigned short* cbh = (unsigned short*)(ws + WS_CBH_OFF);
    int i = (blockIdx.x * 256 + threadIdx.x) * 4;
    float4 x = *(const float4*)(cbks + i);
    ushort4 y;
    y.x = f2bf(x.x); y.y = f2bf(x.y); y.z = f2bf(x.z); y.w = f2bf(x.w);
    *(ushort4*)(cbh + i) = y;
}

// ---------------------------------------------------------------------------
// Kernel A (select): each WAVE autonomously owns 16 rows in registers.
// Writes ONLY the chosen indices. No __syncthreads, ~3 KB LDS.
// Screen B-loads are software-pipelined (double-buffered, prefetch crosses
// chunk boundaries) to keep 8 L2 loads in flight instead of 1.
// ---------------------------------------------------------------------------
__global__ __launch_bounds__(NT, 1) void sel_kernel(
    const float* __restrict__ ze, const float* __restrict__ cbks,
    float* __restrict__ out, float* __restrict__ ws)
{
    __shared__ unsigned long long best64[4 * RW];
    __shared__ int clist[4 * CAPW];
    __shared__ int cc[4];

    const int tid  = threadIdx.x;
    const int w    = tid >> 6;
    const int lane = tid & 63;
    const int r    = lane & 15;
    const int hi   = lane >> 4;
    const int rows0 = blockIdx.x * 64 + w * RW;
    const size_t grow = (size_t)(rows0 + r);

    const float* c2 = ws + WS_C2_OFF;
    const unsigned short* cbh = (const unsigned short*)(ws + WS_CBH_OFF);

    float res[8][8];   // [ks][j]: residual[row r][d = ks*32 + hi*8 + j]

    #pragma unroll
    for (int ks = 0; ks < 8; ++ks) {
        const int d0 = ks * 32 + hi * 8;
        float4 z0 = *(const float4*)(ze + grow * Dd + d0);
        float4 z1 = *(const float4*)(ze + grow * Dd + d0 + 4);
        res[ks][0] = z0.x; res[ks][1] = z0.y; res[ks][2] = z0.z; res[ks][3] = z0.w;
        res[ks][4] = z1.x; res[ks][5] = z1.y; res[ks][6] = z1.z; res[ks][7] = z1.w;
    }

    for (int l = 0; l < Ll; ++l) {
        // ---- np-exact r2 from registers (commutativity-based tree) ----
        float blk[2];
        #pragma unroll
        for (int hb = 0; hb < 2; ++hb) {
            float wv[4];
            #pragma unroll
            for (int L = 0; L < 4; ++L) {
                float a0 = __fmul_rn(res[4*hb][L],     res[4*hb][L]);
                float a1 = __fmul_rn(res[4*hb][4 + L], res[4*hb][4 + L]);
                #pragma unroll
                for (int m = 1; m < 4; ++m) {
                    a0 = __fadd_rn(a0, __fmul_rn(res[4*hb+m][L],     res[4*hb+m][L]));
                    a1 = __fadd_rn(a1, __fmul_rn(res[4*hb+m][4 + L], res[4*hb+m][4 + L]));
                }
                float p = __fadd_rn(a0, a1);
                float q = __fadd_rn(p, __shfl_xor(p, 16));
                wv[L]   = __fadd_rn(q, __shfl_xor(q, 32));
            }
            blk[hb] = __fadd_rn(__fadd_rn(wv[0], wv[1]), __fadd_rn(wv[2], wv[3]));
        }
        const float r2v = __fadd_rn(blk[0], blk[1]);

        if (lane < RW) best64[w * RW + lane] = ~0ull;
        if (lane == 0) cc[w] = 0;

        // ---- bf16 A fragments (in-register) ----
        v8s abf[8];
        #pragma unroll
        for (int ks = 0; ks < 8; ++ks) {
            v8s t;
            #pragma unroll
            for (int j = 0; j < 8; ++j) t[j] = (short)f2bf(res[ks][j]);
            abf[ks] = t;
        }

        const unsigned short* cbh_l = cbh + (size_t)l * Kk * Dd;
        const float* c2l = c2 + l * Kk;
        const float* cb  = cbks + (size_t)l * Kk * Dd;

        // ---- screen: 16 chunks x 64 codes, pipelined B-loads ----
        // lane-invariant part of the B address
        const unsigned short* base_lane = cbh_l + (size_t)r * Dd + hi * 8;
        // load the 4 ct-fragments of (chunk CH, k-slice KS) into BUF
        #define LDB(BUF, CH, KS)                                              \
            _Pragma("unroll")                                                 \
            for (int ct = 0; ct < 4; ++ct)                                    \
                BUF[ct] = *(const v8s*)(base_lane +                           \
                    ((size_t)((CH) * 64 + ct * 16)) * Dd + (KS) * 32);

        float mr[4] = {1e30f, 1e30f, 1e30f, 1e30f};
        v8s bb0[4], bb1[4];
        LDB(bb0, 0, 0);                        // prologue: step (0,0)

        for (int ch = 0; ch < 16; ++ch) {
            const int cbase = ch * 64;
            // hoist c2 loads above the MFMA chain (latency covered by it)
            float c2v[4];
            #pragma unroll
            for (int ct = 0; ct < 4; ++ct) c2v[ct] = c2l[cbase + ct*16 + r];

            v4f acc[4];
            #pragma unroll
            for (int ct = 0; ct < 4; ++ct) acc[ct] = (v4f)(0.f);

            // 8 steps; prefetch step s+1 while MFMA-ing step s.
            // parity: buffer (ks&1) holds step ks (8 steps/chunk keeps it
            // consistent across chunks; ch=15 tail prefetch wraps to ch 0).
            #pragma unroll
            for (int ks = 0; ks < 8; ++ks) {
                const int nch = (ks == 7) ? ((ch + 1) & 15) : ch;
                const int nks = (ks + 1) & 7;
                if ((ks & 1) == 0) {
                    LDB(bb1, nch, nks);
                    #pragma unroll
                    for (int ct = 0; ct < 4; ++ct)
                        acc[ct] = __builtin_amdgcn_mfma_f32_16x16x32_bf16(abf[ks], bb0[ct], acc[ct], 0, 0, 0);
                } else {
                    LDB(bb0, nch, nks);
                    #pragma unroll
                    for (int ct = 0; ct < 4; ++ct)
                        acc[ct] = __builtin_amdgcn_mfma_f32_16x16x32_bf16(abf[ks], bb1[ct], acc[ct], 0, 0, 0);
                }
            }

            // candidate collection: C-layout col=lane&15, row=(lane>>4)*4+reg
            #pragma unroll
            for (int reg = 0; reg < 4; ++reg) {
                const int lrow = hi * 4 + reg;
                float t0 = c2v[0] - 2.f * acc[0][reg];
                float t1 = c2v[1] - 2.f * acc[1][reg];
                float t2 = c2v[2] - 2.f * acc[2][reg];
                float t3 = c2v[3] - 2.f * acc[3][reg];
                float pm = fminf(fminf(t0, t1), fminf(t2, t3));
                pm = fminf(pm, __shfl_xor(pm, 1));
                pm = fminf(pm, __shfl_xor(pm, 2));
                pm = fminf(pm, __shfl_xor(pm, 4));
                pm = fminf(pm, __shfl_xor(pm, 8));
                float nm = fminf(mr[reg], pm);
                mr[reg] = nm;
                float th = nm + MARGIN;
                if (t0 < th) { int p = atomicAdd(&cc[w], 1); if (p < CAPW) clist[w*CAPW+p] = (lrow << 10) | (cbase + r); }
                if (t1 < th) { int p = atomicAdd(&cc[w], 1); if (p < CAPW) clist[w*CAPW+p] = (lrow << 10) | (cbase + 16 + r); }
                if (t2 < th) { int p = atomicAdd(&cc[w], 1); if (p < CAPW) clist[w*CAPW+p] = (lrow << 10) | (cbase + 32 + r); }
                if (t3 < th) { int p = atomicAdd(&cc[w], 1); if (p < CAPW) clist[w*CAPW+p] = (lrow << 10) | (cbase + 48 + r); }
            }
        }
        #undef LDB

        // ---- exact np-order rescore; residual via uniform-exec shfl ----
        {
            int cnt = cc[w];
            const bool ok = (cnt <= CAPW);
            const int total = ok ? cnt : (RW * Kk);
            for (int base = 0; base < total; base += 64) {
                const int ci = base + lane;
                int rr, code;
                if (ok) {
                    int rc = clist[w * CAPW + (ci < cnt ? ci : 0)];
                    rr = rc >> 10; code = rc & 1023;
                } else {
                    rr = ci >> 10; code = ci & 1023;
                }
                const float* cp = cb + (size_t)code * Dd;
                const float r2row = __shfl(r2v, rr);
                float a = 0.f;
                #pragma unroll
                for (int ks = 0; ks < 8; ++ks) {
                    #pragma unroll
                    for (int hh = 0; hh < 4; ++hh) {
                        const int src = rr + (hh << 4);
                        float4 c0 = *(const float4*)(cp + ks * 32 + hh * 8);
                        float4 c1 = *(const float4*)(cp + ks * 32 + hh * 8 + 4);
                        a = __fmaf_rn(__shfl(res[ks][0], src), c0.x, a);
                        a = __fmaf_rn(__shfl(res[ks][1], src), c0.y, a);
                        a = __fmaf_rn(__shfl(res[ks][2], src), c0.z, a);
                        a = __fmaf_rn(__shfl(res[ks][3], src), c0.w, a);
                        a = __fmaf_rn(__shfl(res[ks][4], src), c1.x, a);
                        a = __fmaf_rn(__shfl(res[ks][5], src), c1.y, a);
                        a = __fmaf_rn(__shfl(res[ks][6], src), c1.z, a);
                        a = __fmaf_rn(__shfl(res[ks][7], src), c1.w, a);
                    }
                }
                float s = __fsub_rn(__fadd_rn(r2row, c2l[code]), 2.0f * a);
                if (!ok || ci < cnt) {
                    unsigned long long pk =
                        (((unsigned long long)__float_as_uint(s)) << 32) | (unsigned)code;
                    atomicMin(&best64[w * RW + rr], pk);
                }
            }
        }

        // ---- pick index, update register residual (exact), store idx ----
        const int idx = (int)(best64[w * RW + r] & 0xffffffffu);
        if (lane < RW)
            out[O_IDX + (size_t)(rows0 + lane) * Ll + l] =
                (float)(int)(best64[w * RW + lane] & 0xffffffffu);

        if (l < Ll - 1) {
            const float* qp = cb + (size_t)idx * Dd;
            #pragma unroll
            for (int ks = 0; ks < 8; ++ks) {
                const int d0 = ks * 32 + hi * 8;
                float4 q0 = *(const float4*)(qp + d0);
                float4 q1 = *(const float4*)(qp + d0 + 4);
                res[ks][0] = __fsub_rn(res[ks][0], q0.x);
                res[ks][1] = __fsub_rn(res[ks][1], q0.y);
                res[ks][2] = __fsub_rn(res[ks][2], q0.z);
                res[ks][3] = __fsub_rn(res[ks][3], q0.w);
                res[ks][4] = __fsub_rn(res[ks][4], q1.x);
                res[ks][5] = __fsub_rn(res[ks][5], q1.y);
                res[ks][6] = __fsub_rn(res[ks][6], q1.z);
                res[ks][7] = __fsub_rn(res[ks][7], q1.w);
            }
        }
    }
}

// ---------------------------------------------------------------------------
// Kernel B (materialize): streaming reconstruction from indices.
// ---------------------------------------------------------------------------
__global__ __launch_bounds__(NT, 8) void mat_kernel(
    const float* __restrict__ ze, const float* __restrict__ cbks,
    float* __restrict__ out, float* __restrict__ ws)
{
    const int tid  = threadIdx.x;
    const int w    = tid >> 6;
    const int lane = tid & 63;
    const int wgid = blockIdx.x * 4 + w;      // 0..8191
    const int d0   = lane * 4;

    float ssql[4] = {0.f, 0.f, 0.f, 0.f};

    #pragma unroll 1
    for (int rr = 0; rr < 16; ++rr) {
        const size_t row = (size_t)wgid + (size_t)rr * 8192;

        int idx[4];
        #pragma unroll
        for (int l = 0; l < Ll; ++l)
            idx[l] = (int)out[O_IDX + row * Ll + l];

        float4 q[4];
        #pragma unroll
        for (int l = 0; l < Ll; ++l)
            q[l] = *(const float4*)(cbks + ((size_t)l * Kk + idx[l]) * Dd + d0);

        float4 z = *(const float4*)(ze + row * Dd + d0);
        *(float4*)(out + O_RES + row * Dd + d0) = z;         // res_states[0]

        float4 r = z;
        #pragma unroll
        for (int l = 0; l < Ll; ++l) {
            *(float4*)(out + O_QSTK + (row * Ll + l) * Dd + d0) = q[l];
            r.x = __fsub_rn(r.x, q[l].x);
            r.y = __fsub_rn(r.y, q[l].y);
            r.z = __fsub_rn(r.z, q[l].z);
            r.w = __fsub_rn(r.w, q[l].w);
            *(float4*)(out + O_RES + ((size_t)(l + 1) * Bsz + row) * Dd + d0) = r;
            ssql[l] += r.x * r.x + r.y * r.y + r.z * r.z + r.w * r.w;
        }

        float4 qs = make_float4(z.x - r.x, z.y - r.y, z.z - r.z, z.w - r.w);
        *(float4*)(out + O_QSUM + row * Dd + d0) = qs;
        float4 qq = make_float4(z.x + (qs.x - z.x), z.y + (qs.y - z.y),
                                z.z + (qs.z - z.z), z.w + (qs.w - z.w));
        *(float4*)(out + O_QSQ + row * Dd + d0) = qq;
    }

    #pragma unroll
    for (int l = 0; l < Ll; ++l) {
        float s = ssql[l];
        #pragma unroll
        for (int m = 32; m; m >>= 1) s += __shfl_xor(s, m);
        if (lane == 0) ws[(size_t)wgid * 4 + l] = s;
    }
}

// ---------------------------------------------------------------------------
// loss: deterministic reduction of per-wave partials -> 3 scalars
// ---------------------------------------------------------------------------
__global__ void loss_kernel(const float* __restrict__ ws, float* __restrict__ out) {
    __shared__ float red[Ll * 4];
    int tid = threadIdx.x;
    int lane = tid & 63, w = tid >> 6;
    for (int l = 0; l < Ll; ++l) {
        float s = 0.f;
        for (int i = tid; i < NWG * 4; i += 256) s += ws[i * 4 + l];
        #pragma unroll
        for (int m = 32; m; m >>= 1) s += __shfl_xor(s, m);
        if (lane == 0) red[l * 4 + w] = s;
    }
    __syncthreads();
    if (tid == 0) {
        float tot = 0.f;
        for (int l = 0; l < Ll; ++l)
            tot += red[l * 4 + 0] + red[l * 4 + 1] + red[l * 4 + 2] + red[l * 4 + 3];
        float cm = tot / (float)((size_t)Ll * Bsz * Dd);
        out[O_LOSS + 0] = cm;                    // commitment_loss
        out[O_LOSS + 1] = cm;                    // codebook_loss
        out[O_LOSS + 2] = 0.25f * cm + cm;       // quantization_loss
    }
}

extern "C" void kernel_launch(void* const* d_in, const int* in_sizes, int n_in,
                              void* d_out, int out_size, void* d_ws, size_t ws_size,
                              hipStream_t stream) {
    (void)in_sizes; (void)n_in; (void)out_size; (void)ws_size;
    const float* ze   = (const float*)d_in[0];
    const float* cbks = (const float*)d_in[1];
    float* out = (float*)d_out;
    float* ws  = (float*)d_ws;

    hipLaunchKernelGGL(prep_kernel, dim3(16), dim3(256), 0, stream, cbks, ws);
    hipLaunchKernelGGL(cvt_kernel, dim3(Ll * Kk * Dd / 1024), dim3(256), 0, stream, cbks, ws);
    hipLaunchKernelGGL(sel_kernel, dim3(NWG), dim3(NT), 0, stream, ze, cbks, out, ws);
    hipLaunchKernelGGL(mat_kernel, dim3(NWG), dim3(NT), 0, stream, ze, cbks, out, ws);
    hipLaunchKernelGGL(loss_kernel, dim3(1), dim3(256), 0, stream, ws, out);
}